// Round 1
// baseline (3718.643 us; speedup 1.0000x reference)
//
#include <hip/hip_runtime.h>
#include <hip/hip_bf16.h>
#include <math.h>

// ---- problem constants ----
#define B_      8
#define M_      8192
#define E_      128
#define EPL     64
#define BM_     (B_ * M_)      // 65536 beats
#define BEAT_D  256
#define EP_D    384
#define RHY_D   128
#define DAY_D   512
#define NCODES  512
#define CODE_D  64
#define TOK_H   512
#define WINF    246            // 240 window + 6 metadata

// out layout (floats)
#define OFF_DAY   33554432L
#define OFF_EPCTX 33558528L
#define OFF_CODE  34082816L
#define OFF_VQ    34148352L

__device__ __forceinline__ float gelu_t(float x) {
  float x3 = x * x * x;
  return 0.5f * x * (1.0f + tanhf(0.7978845608028654f * (x + 0.044715f * x3)));
}

// A-source gather modes:
// 0: plain row-major M x K (lda = K)
// 1: tokenizer concat: windows (m,240) | metadata (m,6)
// 2: beat_proj concat: BE(256) | CTX(384)*ctx_valid | RHY(128)
// 3: day concat: ep_wave(384) | ep_rhy(128)
template<int AMODE>
__device__ __forceinline__ float load_A(const float* __restrict__ A,
                                        const float* __restrict__ A2,
                                        const float* __restrict__ A3,
                                        const int* __restrict__ neps,
                                        int m, int k, int K) {
  if (AMODE == 0) {
    return A[(long)m * K + k];
  } else if (AMODE == 1) {
    if (k < 240) return A[(long)m * 240 + k];
    return A2[(long)m * 6 + (k - 240)];
  } else if (AMODE == 2) {
    if (k < 256) return A[(long)m * 256 + k];
    if (k < 640) {
      bool v = (m & (M_ - 1)) < neps[m >> 13] * EPL;
      return v ? A2[(long)m * 384 + (k - 256)] : 0.0f;
    }
    return A3[(long)m * 128 + (k - 640)];
  } else {
    if (k < 384) return A[(long)m * 384 + k];
    return A2[(long)m * 128 + (k - 384)];
  }
}

// Tiled fp32 GEMM: C(MxN) = epilogue(A(MxK) @ B(KxN) + bias)
// tile 128(M) x 64(N), 256 threads, each thread 8x4, BK=16
template<int AMODE, bool DOGELU, bool HASBIAS, bool EPMASK>
__global__ __launch_bounds__(256) void gemm_k(
    const float* __restrict__ A, const float* __restrict__ A2,
    const float* __restrict__ A3, const int* __restrict__ neps,
    const float* __restrict__ Bm, const float* __restrict__ bias,
    float* __restrict__ C, int M, int N, int K)
{
  __shared__ __align__(16) float As[16][132];  // [k][m], pad 4
  __shared__ __align__(16) float Bs[16][68];   // [k][n], pad 4

  const int bn = blockIdx.x * 64;
  const int bm = blockIdx.y * 128;
  const int tid = threadIdx.x;
  const int tx = tid & 15;        // 0..15 -> 4 cols each
  const int ty = tid >> 4;        // 0..15 -> 8 rows each

  float acc[8][4];
#pragma unroll
  for (int i = 0; i < 8; ++i)
#pragma unroll
    for (int j = 0; j < 4; ++j) acc[i][j] = 0.f;

  for (int k0 = 0; k0 < K; k0 += 16) {
    // stage A: 128 rows x 16 k  (2048 elems, 8/thread)
    {
      int kk = tid & 15, r0 = tid >> 4;
#pragma unroll
      for (int i = 0; i < 8; ++i) {
        int row = r0 + i * 16;
        int gk = k0 + kk;
        float v = 0.f;
        if (gk < K) v = load_A<AMODE>(A, A2, A3, neps, bm + row, gk, K);
        As[kk][row] = v;
      }
    }
    // stage B: 16 k x 64 n
    {
      int c = tid & 63, r0 = tid >> 6;
#pragma unroll
      for (int i = 0; i < 4; ++i) {
        int kk = r0 + i * 4;
        int gk = k0 + kk;
        float v = 0.f;
        if (gk < K) v = Bm[(long)gk * N + bn + c];
        Bs[kk][c] = v;
      }
    }
    __syncthreads();
#pragma unroll
    for (int kk = 0; kk < 16; ++kk) {
      float4 a0 = *reinterpret_cast<const float4*>(&As[kk][ty * 8]);
      float4 a1 = *reinterpret_cast<const float4*>(&As[kk][ty * 8 + 4]);
      float4 bv = *reinterpret_cast<const float4*>(&Bs[kk][tx * 4]);
      float av[8] = {a0.x, a0.y, a0.z, a0.w, a1.x, a1.y, a1.z, a1.w};
      float bb[4] = {bv.x, bv.y, bv.z, bv.w};
#pragma unroll
      for (int i = 0; i < 8; ++i)
#pragma unroll
        for (int j = 0; j < 4; ++j) acc[i][j] += av[i] * bb[j];
    }
    __syncthreads();
  }

  // epilogue
#pragma unroll
  for (int i = 0; i < 8; ++i) {
    int gm = bm + ty * 8 + i;
    bool valid = true;
    if (EPMASK) valid = ((gm & (E_ - 1)) < neps[gm >> 7]);
    float4 o;
    float* op = &o.x;
#pragma unroll
    for (int j = 0; j < 4; ++j) {
      int gn = bn + tx * 4 + j;
      float v = acc[i][j];
      if (HASBIAS) v += bias[gn];
      if (DOGELU) v = gelu_t(v);
      if (EPMASK && !valid) v = 0.f;
      op[j] = v;
    }
    *reinterpret_cast<float4*>(&C[(long)gm * N + bn + tx * 4]) = o;
  }
}

// VQ: per beat, argmin over 512 codes of |z|^2 - 2 z.c + |c|^2 ; vq partial = min dist
__global__ __launch_bounds__(256) void vq_k(
    const float* __restrict__ Z, const float* __restrict__ cb,
    int* __restrict__ cidx, float* __restrict__ code_f,
    float* __restrict__ vq_accum, float inv_cnt)
{
  __shared__ __align__(16) float cbs[128 * 64];  // 32 KB chunk
  __shared__ float c2s[512];
  __shared__ float red[256];
  const int t = threadIdx.x;
  const int beat = blockIdx.x * 256 + t;

  // |c|^2 for all codes, once
#pragma unroll
  for (int r = 0; r < 2; ++r) {
    int c = t + r * 256;
    float s = 0.f;
    for (int d = 0; d < 64; d += 4) {
      float4 v = *reinterpret_cast<const float4*>(&cb[(long)c * 64 + d]);
      s += v.x * v.x + v.y * v.y + v.z * v.z + v.w * v.w;
    }
    c2s[c] = s;
  }

  float z[64];
  float z2 = 0.f;
#pragma unroll
  for (int d = 0; d < 64; d += 4) {
    float4 v = *reinterpret_cast<const float4*>(&Z[(long)beat * 64 + d]);
    z[d] = v.x; z[d + 1] = v.y; z[d + 2] = v.z; z[d + 3] = v.w;
    z2 += v.x * v.x + v.y * v.y + v.z * v.z + v.w * v.w;
  }

  float best = 3.4e38f;
  int bi = 0;
  for (int c0 = 0; c0 < NCODES; c0 += 128) {
    __syncthreads();  // prev chunk fully consumed (also covers c2s on first iter)
#pragma unroll
    for (int i = 0; i < 8; ++i) {
      int idx = (t + i * 256) * 4;
      *reinterpret_cast<float4*>(&cbs[idx]) =
          *reinterpret_cast<const float4*>(&cb[(long)c0 * 64 + idx]);
    }
    __syncthreads();
    for (int c = 0; c < 128; ++c) {
      const float* cp = &cbs[c * 64];
      float d0 = 0.f, d1 = 0.f, d2 = 0.f, d3 = 0.f;
#pragma unroll
      for (int d = 0; d < 64; d += 4) {
        d0 += z[d] * cp[d];
        d1 += z[d + 1] * cp[d + 1];
        d2 += z[d + 2] * cp[d + 2];
        d3 += z[d + 3] * cp[d + 3];
      }
      float dist = z2 - 2.f * ((d0 + d1) + (d2 + d3)) + c2s[c0 + c];
      if (dist < best) { best = dist; bi = c0 + c; }
    }
  }
  cidx[beat] = bi;
  code_f[beat] = (float)bi;

  red[t] = best;  // sum_d (z-q)^2 == min dist
  __syncthreads();
  for (int s = 128; s > 0; s >>= 1) {
    if (t < s) red[t] += red[t + s];
    __syncthreads();
  }
  if (t == 0) atomicAdd(vq_accum, red[0] * inv_cnt);
}

__global__ void rhythm_k(const int* __restrict__ cidx, const int* __restrict__ rr,
                         const int* __restrict__ rrp, const float* __restrict__ hs,
                         const float* __restrict__ hc, const float* __restrict__ cemb,
                         const float* __restrict__ rremb, const float* __restrict__ rrpemb,
                         const float* __restrict__ hw, float* __restrict__ out)
{
  int i = blockIdx.x * blockDim.x + threadIdx.x;
  if (i >= BM_ * RHY_D) return;
  int m = i >> 7, d = i & 127;
  float v = cemb[cidx[m] * RHY_D + d] + rremb[rr[m] * RHY_D + d] +
            rrpemb[rrp[m] * RHY_D + d] + hs[m] * hw[d] + hc[m] * hw[RHY_D + d];
  out[i] = gelu_t(v);
}

__global__ __launch_bounds__(512) void ep_mean_k(
    const float* __restrict__ ctx, const float* __restrict__ rhy,
    const int* __restrict__ neps, float* __restrict__ ctx_mean,
    float* __restrict__ rhy_mean)
{
  int be = blockIdx.x;
  int t = threadIdx.x;
  bool valid = (be & (E_ - 1)) < neps[be >> 7];
  if (t < EP_D) {
    float s = 0.f;
    for (int l = 0; l < EPL; ++l) s += ctx[((long)be * EPL + l) * EP_D + t];
    ctx_mean[be * EP_D + t] = s * (1.0f / EPL);   // unmasked (feeds eptok)
  } else if (t < EP_D + RHY_D) {
    int d = t - EP_D;
    float s = 0.f;
    for (int l = 0; l < EPL; ++l) s += rhy[((long)be * EPL + l) * RHY_D + d];
    rhy_mean[be * RHY_D + d] = valid ? s * (1.0f / EPL) : 0.f;  // masked
  }
}

__global__ __launch_bounds__(512) void day_k(const float* __restrict__ ec,
                                             const int* __restrict__ neps,
                                             float* __restrict__ day)
{
  int b = blockIdx.x, h = threadIdx.x;
  int n = neps[b];
  float s = 0.f;
  for (int e = 0; e < n; ++e) s += ec[((long)b * E_ + e) * DAY_D + h];
  day[b * DAY_D + h] = s / (float)(n > 0 ? n : 1);
}

extern "C" void kernel_launch(void* const* d_in, const int* in_sizes, int n_in,
                              void* d_out, int out_size, void* d_ws, size_t ws_size,
                              hipStream_t stream)
{
  (void)in_sizes; (void)n_in; (void)out_size; (void)ws_size;
  const float* windows  = (const float*)d_in[0];
  const float* metadata = (const float*)d_in[1];
  const int*   n_eps    = (const int*)d_in[3];
  const int*   rr_bins  = (const int*)d_in[4];
  const int*   rrp_bins = (const int*)d_in[5];
  const float* hour_sin = (const float*)d_in[6];
  const float* hour_cos = (const float*)d_in[7];
  const float* w_tok1 = (const float*)d_in[8];
  const float* b_tok1 = (const float*)d_in[9];
  const float* w_tok2 = (const float*)d_in[10];
  const float* b_tok2 = (const float*)d_in[11];
  const float* w_code = (const float*)d_in[12];
  const float* codebook = (const float*)d_in[13];
  const float* w_ep1 = (const float*)d_in[14];
  const float* b_ep1 = (const float*)d_in[15];
  const float* w_ep2 = (const float*)d_in[16];
  const float* b_ep2 = (const float*)d_in[17];
  const float* w_eptok = (const float*)d_in[18];
  const float* b_eptok = (const float*)d_in[19];
  const float* code_emb = (const float*)d_in[20];
  const float* rr_emb = (const float*)d_in[21];
  const float* rrp_emb = (const float*)d_in[22];
  const float* hour_w = (const float*)d_in[23];
  const float* w_fuse = (const float*)d_in[24];
  const float* b_fuse = (const float*)d_in[25];
  const float* w_day = (const float*)d_in[26];
  const float* b_day = (const float*)d_in[27];
  const float* w_bp1 = (const float*)d_in[28];
  const float* b_bp1 = (const float*)d_in[29];
  const float* w_bp2 = (const float*)d_in[30];
  const float* b_bp2 = (const float*)d_in[31];

  float* out = (float*)d_out;
  float* ws  = (float*)d_ws;
  // workspace layout (floats) — peak ~258 MB
  float* H     = ws;               // 33,554,432 (H / HE / BP_hidden, reused)
  float* BE    = ws + 33554432L;   // 16,777,216
  float* Z     = ws + 50331648L;   //  4,194,304
  float* RHY   = ws + 54525952L;   //  8,388,608
  int*   CIDX  = (int*)(ws + 62914560L);   // 65,536
  float* CMEAN = ws + 62980096L;   // 393,216
  float* RMEAN = ws + 63373312L;   // 131,072
  float* EPW   = ws + 63504384L;   // 393,216
  float* FUSED = ws + 63897600L;   // 524,288
  float* CTX   = out;              // scratch inside beat_repr region (dead before G7)

  hipMemsetAsync((void*)(out + OFF_VQ), 0, sizeof(float), stream);

  dim3 blk(256);
  // G1: H = gelu(X @ w_tok1 + b_tok1)   (65536 x 246 x 512)
  gemm_k<1, true, true, false><<<dim3(TOK_H / 64, BM_ / 128), blk, 0, stream>>>(
      windows, metadata, nullptr, nullptr, w_tok1, b_tok1, H, BM_, TOK_H, WINF);
  // G2: BE = H @ w_tok2 + b_tok2        (65536 x 512 x 256)
  gemm_k<0, false, true, false><<<dim3(BEAT_D / 64, BM_ / 128), blk, 0, stream>>>(
      H, nullptr, nullptr, nullptr, w_tok2, b_tok2, BE, BM_, BEAT_D, TOK_H);
  // G3: Z = BE @ w_code                 (65536 x 256 x 64)
  gemm_k<0, false, false, false><<<dim3(CODE_D / 64, BM_ / 128), blk, 0, stream>>>(
      BE, nullptr, nullptr, nullptr, w_code, nullptr, Z, BM_, CODE_D, BEAT_D);
  // VQ: code_idx + vq_loss
  vq_k<<<dim3(BM_ / 256), blk, 0, stream>>>(Z, codebook, CIDX, out + OFF_CODE,
                                            out + OFF_VQ, 1.0f / (float)(BM_ * CODE_D));
  // rhythm branch
  rhythm_k<<<dim3((BM_ * RHY_D) / 256), blk, 0, stream>>>(
      CIDX, rr_bins, rrp_bins, hour_sin, hour_cos, code_emb, rr_emb, rrp_emb, hour_w, RHY);
  // G4: HE = gelu(BE @ w_ep1 + b_ep1)   (into H region)
  gemm_k<0, true, true, false><<<dim3(EP_D / 64, BM_ / 128), blk, 0, stream>>>(
      BE, nullptr, nullptr, nullptr, w_ep1, b_ep1, H, BM_, EP_D, BEAT_D);
  // G5: CTX = HE @ w_ep2 + b_ep2        (into d_out scratch)
  gemm_k<0, false, true, false><<<dim3(EP_D / 64, BM_ / 128), blk, 0, stream>>>(
      H, nullptr, nullptr, nullptr, w_ep2, b_ep2, CTX, BM_, EP_D, EP_D);
  // episode means
  ep_mean_k<<<dim3(B_ * E_), dim3(512), 0, stream>>>(CTX, RHY, n_eps, CMEAN, RMEAN);
  // E2: ep_wave = mask(CMEAN @ w_eptok + b_eptok)
  gemm_k<0, false, true, true><<<dim3(EP_D / 64, (B_ * E_) / 128), blk, 0, stream>>>(
      CMEAN, nullptr, nullptr, n_eps, w_eptok, b_eptok, EPW, B_ * E_, EP_D, EP_D);
  // E3: FUSED = gelu([ep_wave|ep_rhy] @ w_fuse + b_fuse)
  gemm_k<3, true, true, false><<<dim3(DAY_D / 64, (B_ * E_) / 128), blk, 0, stream>>>(
      EPW, RMEAN, nullptr, nullptr, w_fuse, b_fuse, FUSED, B_ * E_, DAY_D, EP_D + RHY_D);
  // E4: episode_ctx = FUSED @ w_day + b_day  -> d_out
  gemm_k<0, false, true, false><<<dim3(DAY_D / 64, (B_ * E_) / 128), blk, 0, stream>>>(
      FUSED, nullptr, nullptr, nullptr, w_day, b_day, out + OFF_EPCTX, B_ * E_, DAY_D, DAY_D);
  // E5: day_embed
  day_k<<<dim3(B_), dim3(DAY_D), 0, stream>>>(out + OFF_EPCTX, n_eps, out + OFF_DAY);
  // G6: BP_hidden = gelu(cat @ w_bp1 + b_bp1)  (into H region)
  gemm_k<2, true, true, false><<<dim3(DAY_D / 64, BM_ / 128), blk, 0, stream>>>(
      BE, CTX, RHY, n_eps, w_bp1, b_bp1, H, BM_, DAY_D, BEAT_D + EP_D + RHY_D);
  // G7: beat_repr = BP_hidden @ w_bp2 + b_bp2  -> d_out
  gemm_k<0, false, true, false><<<dim3(DAY_D / 64, BM_ / 128), blk, 0, stream>>>(
      H, nullptr, nullptr, nullptr, w_bp2, b_bp2, out, BM_, DAY_D, DAY_D);
}

// Round 3
// 1997.511 us; speedup vs baseline: 1.8616x; 1.8616x over previous
//
#include <hip/hip_runtime.h>
#include <hip/hip_bf16.h>
#include <math.h>

// ---- problem constants ----
#define B_      8
#define M_      8192
#define E_      128
#define EPL     64
#define BM_     (B_ * M_)      // 65536 beats
#define BEAT_D  256
#define EP_D    384
#define RHY_D   128
#define DAY_D   512
#define NCODES  512
#define CODE_D  64
#define TOK_H   512
#define WINF    246

// out layout (floats)
#define OFF_DAY   33554432L
#define OFF_EPCTX 33558528L
#define OFF_CODE  34082816L
#define OFF_VQ    34148352L

typedef unsigned short ushort_t;
typedef __attribute__((ext_vector_type(8))) short short8;
typedef __attribute__((ext_vector_type(4))) float floatx4;

__device__ __forceinline__ float gelu_t(float x) {
  float x3 = x * x * x;
  return 0.5f * x * (1.0f + tanhf(0.7978845608028654f * (x + 0.044715f * x3)));
}

__device__ __forceinline__ ushort_t f2bf(float f) {
  union { float f; unsigned u; } x; x.f = f;
  unsigned r = (x.u + 0x7fffu + ((x.u >> 16) & 1u)) >> 16;
  return (ushort_t)r;
}
__device__ __forceinline__ float bf2f(ushort_t u) {
  union { unsigned u; float f; } x; x.u = ((unsigned)u) << 16;
  return x.f;
}

// ======================= fp32 GEMMs =======================
// A-source gather modes (fp32):
// 0: plain row-major, 1: windows|metadata, 3: ep_wave|ep_rhy
template<int AMODE>
__device__ __forceinline__ float load_A(const float* __restrict__ A,
                                        const float* __restrict__ A2,
                                        int m, int k, int K) {
  if (AMODE == 0) {
    return A[(long)m * K + k];
  } else if (AMODE == 1) {
    if (k < 240) return A[(long)m * 240 + k];
    return A2[(long)m * 6 + (k - 240)];
  } else {
    if (k < 384) return A[(long)m * 384 + k];
    return A2[(long)m * 128 + (k - 384)];
  }
}

// Big fp32 GEMM: tile 128x128, 256 thr, 8x8/thread, BK=16. N%128==0, M%128==0.
template<int AMODE, bool DOGELU, bool HASBIAS, bool WRITEBF16>
__global__ __launch_bounds__(256) void gemm_f32_big(
    const float* __restrict__ A, const float* __restrict__ A2,
    const float* __restrict__ Bm, const float* __restrict__ bias,
    float* __restrict__ C, ushort_t* __restrict__ Ch, int M, int N, int K)
{
  __shared__ __align__(16) float As[16][132];
  __shared__ __align__(16) float Bs[16][132];

  const int bn = blockIdx.x * 128;
  const int bm = blockIdx.y * 128;
  const int tid = threadIdx.x;
  const int tx = tid & 15;
  const int ty = tid >> 4;

  float acc[8][8];
#pragma unroll
  for (int i = 0; i < 8; ++i)
#pragma unroll
    for (int j = 0; j < 8; ++j) acc[i][j] = 0.f;

  for (int k0 = 0; k0 < K; k0 += 16) {
    {
      int kk = tid & 15, r0 = tid >> 4;
      int gk = k0 + kk;
      bool kin = (gk < K);
#pragma unroll
      for (int i = 0; i < 8; ++i) {
        int row = r0 + i * 16;
        As[kk][row] = kin ? load_A<AMODE>(A, A2, bm + row, gk, K) : 0.f;
      }
    }
    {
#pragma unroll
      for (int i = 0; i < 8; ++i) {
        int idx = tid + i * 256;
        int kk = idx >> 7, c = idx & 127;
        int gk = k0 + kk;
        Bs[kk][c] = (gk < K) ? Bm[(long)gk * N + bn + c] : 0.f;
      }
    }
    __syncthreads();
#pragma unroll
    for (int kk = 0; kk < 16; ++kk) {
      float4 a0 = *reinterpret_cast<const float4*>(&As[kk][ty * 8]);
      float4 a1 = *reinterpret_cast<const float4*>(&As[kk][ty * 8 + 4]);
      float4 b0 = *reinterpret_cast<const float4*>(&Bs[kk][tx * 8]);
      float4 b1 = *reinterpret_cast<const float4*>(&Bs[kk][tx * 8 + 4]);
      float av[8] = {a0.x, a0.y, a0.z, a0.w, a1.x, a1.y, a1.z, a1.w};
      float bv[8] = {b0.x, b0.y, b0.z, b0.w, b1.x, b1.y, b1.z, b1.w};
#pragma unroll
      for (int i = 0; i < 8; ++i)
#pragma unroll
        for (int j = 0; j < 8; ++j) acc[i][j] += av[i] * bv[j];
    }
    __syncthreads();
  }

#pragma unroll
  for (int i = 0; i < 8; ++i) {
    int gm = bm + ty * 8 + i;
    float vout[8];
#pragma unroll
    for (int j = 0; j < 8; ++j) {
      int gn = bn + tx * 8 + j;
      float v = acc[i][j];
      if (HASBIAS) v += bias[gn];
      if (DOGELU) v = gelu_t(v);
      vout[j] = v;
    }
    *reinterpret_cast<float4*>(&C[(long)gm * N + bn + tx * 8]) =
        make_float4(vout[0], vout[1], vout[2], vout[3]);
    *reinterpret_cast<float4*>(&C[(long)gm * N + bn + tx * 8 + 4]) =
        make_float4(vout[4], vout[5], vout[6], vout[7]);
    if (WRITEBF16) {
      union { ushort_t u[8]; uint4 v; } p;
#pragma unroll
      for (int j = 0; j < 8; ++j) p.u[j] = f2bf(vout[j]);
      *reinterpret_cast<uint4*>(&Ch[(long)gm * N + bn + tx * 8]) = p.v;
    }
  }
}

// Small fp32 GEMM: tile 128x64, 8x4/thread. Used for G3/E2/E3/E4.
template<int AMODE, bool DOGELU, bool HASBIAS, bool EPMASK>
__global__ __launch_bounds__(256) void gemm_k(
    const float* __restrict__ A, const float* __restrict__ A2,
    const int* __restrict__ neps,
    const float* __restrict__ Bm, const float* __restrict__ bias,
    float* __restrict__ C, int M, int N, int K)
{
  __shared__ __align__(16) float As[16][132];
  __shared__ __align__(16) float Bs[16][68];

  const int bn = blockIdx.x * 64;
  const int bm = blockIdx.y * 128;
  const int tid = threadIdx.x;
  const int tx = tid & 15;
  const int ty = tid >> 4;

  float acc[8][4];
#pragma unroll
  for (int i = 0; i < 8; ++i)
#pragma unroll
    for (int j = 0; j < 4; ++j) acc[i][j] = 0.f;

  for (int k0 = 0; k0 < K; k0 += 16) {
    {
      int kk = tid & 15, r0 = tid >> 4;
      int gk = k0 + kk;
      bool kin = (gk < K);
#pragma unroll
      for (int i = 0; i < 8; ++i) {
        int row = r0 + i * 16;
        As[kk][row] = kin ? load_A<AMODE>(A, A2, bm + row, gk, K) : 0.f;
      }
    }
    {
      int c = tid & 63, r0 = tid >> 6;
#pragma unroll
      for (int i = 0; i < 4; ++i) {
        int kk = r0 + i * 4;
        int gk = k0 + kk;
        Bs[kk][c] = (gk < K) ? Bm[(long)gk * N + bn + c] : 0.f;
      }
    }
    __syncthreads();
#pragma unroll
    for (int kk = 0; kk < 16; ++kk) {
      float4 a0 = *reinterpret_cast<const float4*>(&As[kk][ty * 8]);
      float4 a1 = *reinterpret_cast<const float4*>(&As[kk][ty * 8 + 4]);
      float4 bv = *reinterpret_cast<const float4*>(&Bs[kk][tx * 4]);
      float av[8] = {a0.x, a0.y, a0.z, a0.w, a1.x, a1.y, a1.z, a1.w};
      float bb[4] = {bv.x, bv.y, bv.z, bv.w};
#pragma unroll
      for (int i = 0; i < 8; ++i)
#pragma unroll
        for (int j = 0; j < 4; ++j) acc[i][j] += av[i] * bb[j];
    }
    __syncthreads();
  }

#pragma unroll
  for (int i = 0; i < 8; ++i) {
    int gm = bm + ty * 8 + i;
    bool valid = true;
    if (EPMASK) valid = ((gm & (E_ - 1)) < neps[gm >> 7]);
    float4 o;
    float* op = &o.x;
#pragma unroll
    for (int j = 0; j < 4; ++j) {
      int gn = bn + tx * 4 + j;
      float v = acc[i][j];
      if (HASBIAS) v += bias[gn];
      if (DOGELU) v = gelu_t(v);
      if (EPMASK && !valid) v = 0.f;
      op[j] = v;
    }
    *reinterpret_cast<float4*>(&C[(long)gm * N + bn + tx * 4]) = o;
  }
}

// ======================= bf16 MFMA GEMM =======================
// C(MxN) = epi(A(MxK)_bf16 @ BT(NxK)_bf16 + bias). M%128==0, N%128==0, K%32==0.
// tile 128x128, 4 waves (2x2), each wave 64x64 via 4x4 mfma_f32_16x16x32_bf16.
// AMODE: 0 plain A; 1 concat [BEh(256)|CTXh(384)|RHYh(128)] (k0 never straddles).
// OUTM: 0 -> bf16 Ch; 1 -> fp32 C.
template<int AMODE, bool DOGELU, bool BEATMASK, int OUTM>
__global__ __launch_bounds__(256) void gemm_bf16(
    const ushort_t* __restrict__ A, const ushort_t* __restrict__ A2,
    const ushort_t* __restrict__ A3, const int* __restrict__ neps,
    const ushort_t* __restrict__ BT, const float* __restrict__ bias,
    float* __restrict__ C, ushort_t* __restrict__ Ch, int N, int K)
{
  __shared__ __align__(16) ushort_t As[128 * 40 + 8];
  __shared__ __align__(16) ushort_t Bs[128 * 40 + 8];

  const int bn = blockIdx.x * 128;
  const int bm = blockIdx.y * 128;
  const int tid = threadIdx.x;
  const int lane = tid & 63;
  const int wave = tid >> 6;
  const int wm = wave & 1;
  const int wn = wave >> 1;
  const int lm = lane & 15;
  const int q  = lane >> 4;

  floatx4 acc[4][4];
#pragma unroll
  for (int i = 0; i < 4; ++i)
#pragma unroll
    for (int j = 0; j < 4; ++j) acc[i][j] = (floatx4)0.f;

  for (int k0 = 0; k0 < K; k0 += 32) {
    const ushort_t* srcA; int ldA, cA;
    if (AMODE == 0) { srcA = A; ldA = K; cA = k0; }
    else {
      if (k0 < 256)      { srcA = A;  ldA = 256; cA = k0; }
      else if (k0 < 640) { srcA = A2; ldA = 384; cA = k0 - 256; }
      else               { srcA = A3; ldA = 128; cA = k0 - 640; }
    }
#pragma unroll
    for (int i = 0; i < 2; ++i) {
      int c = tid + i * 256;
      int r = c >> 2, h = c & 3;
      float4 v = *reinterpret_cast<const float4*>(&srcA[(long)(bm + r) * ldA + cA + h * 8]);
      *reinterpret_cast<float4*>(&As[r * 40 + h * 8]) = v;
    }
#pragma unroll
    for (int i = 0; i < 2; ++i) {
      int c = tid + i * 256;
      int r = c >> 2, h = c & 3;
      float4 v = *reinterpret_cast<const float4*>(&BT[(long)(bn + r) * K + k0 + h * 8]);
      *reinterpret_cast<float4*>(&Bs[r * 40 + h * 8]) = v;
    }
    __syncthreads();

    short8 af[4], bf[4];
#pragma unroll
    for (int i = 0; i < 4; ++i) {
      int mr = wm * 64 + i * 16 + lm;
      af[i] = *reinterpret_cast<const short8*>(&As[mr * 40 + q * 8]);
      int nr = wn * 64 + i * 16 + lm;
      bf[i] = *reinterpret_cast<const short8*>(&Bs[nr * 40 + q * 8]);
    }
#pragma unroll
    for (int i = 0; i < 4; ++i)
#pragma unroll
      for (int j = 0; j < 4; ++j)
        acc[i][j] = __builtin_amdgcn_mfma_f32_16x16x32_bf16(af[i], bf[j], acc[i][j], 0, 0, 0);
    __syncthreads();
  }

  // epilogue: C/D layout col = lane&15, row = q*4 + reg  [m89]
#pragma unroll
  for (int j = 0; j < 4; ++j) {
    int gn = bn + wn * 64 + j * 16 + lm;
    float bv = bias[gn];
#pragma unroll
    for (int i = 0; i < 4; ++i) {
#pragma unroll
      for (int r = 0; r < 4; ++r) {
        int gm = bm + wm * 64 + i * 16 + q * 4 + r;
        float v = acc[i][j][r] + bv;
        if (DOGELU) v = gelu_t(v);
        if (BEATMASK) {
          bool ok = (gm & (M_ - 1)) < neps[gm >> 13] * EPL;
          if (!ok) v = 0.f;
        }
        if (OUTM == 0) Ch[(long)gm * N + gn] = f2bf(v);
        else           C[(long)gm * N + gn] = v;
      }
    }
  }
}

// weight transpose + bf16 convert: w (K,N) fp32 -> wT (N,K) bf16
__global__ void wtrans_k(const float* __restrict__ w, ushort_t* __restrict__ wT,
                         int K, int N)
{
  int id = blockIdx.x * blockDim.x + threadIdx.x;
  if (id >= K * N) return;
  int k = id / N, n = id - k * N;
  wT[(long)n * K + k] = f2bf(w[id]);
}

// ======================= VQ =======================
__global__ __launch_bounds__(256) void vq_k(
    const float* __restrict__ Z, const float* __restrict__ cb,
    int* __restrict__ cidx, float* __restrict__ code_f,
    float* __restrict__ vq_accum, float inv_cnt)
{
  __shared__ __align__(16) float cbs[128 * 64];
  __shared__ float c2s[512];
  __shared__ float red[256];
  const int t = threadIdx.x;
  const int beat = blockIdx.x * 256 + t;

#pragma unroll
  for (int r = 0; r < 2; ++r) {
    int c = t + r * 256;
    float s = 0.f;
    for (int d = 0; d < 64; d += 4) {
      float4 v = *reinterpret_cast<const float4*>(&cb[(long)c * 64 + d]);
      s += v.x * v.x + v.y * v.y + v.z * v.z + v.w * v.w;
    }
    c2s[c] = s;
  }

  float z[64];
  float z2 = 0.f;
#pragma unroll
  for (int d = 0; d < 64; d += 4) {
    float4 v = *reinterpret_cast<const float4*>(&Z[(long)beat * 64 + d]);
    z[d] = v.x; z[d + 1] = v.y; z[d + 2] = v.z; z[d + 3] = v.w;
    z2 += v.x * v.x + v.y * v.y + v.z * v.z + v.w * v.w;
  }

  float best = 3.4e38f;
  int bi = 0;
  for (int c0 = 0; c0 < NCODES; c0 += 128) {
    __syncthreads();
#pragma unroll
    for (int i = 0; i < 8; ++i) {
      int idx = (t + i * 256) * 4;
      *reinterpret_cast<float4*>(&cbs[idx]) =
          *reinterpret_cast<const float4*>(&cb[(long)c0 * 64 + idx]);
    }
    __syncthreads();
    for (int c = 0; c < 128; ++c) {
      const float* cp = &cbs[c * 64];
      float d0 = 0.f, d1 = 0.f, d2 = 0.f, d3 = 0.f;
#pragma unroll
      for (int d = 0; d < 64; d += 4) {
        d0 += z[d] * cp[d];
        d1 += z[d + 1] * cp[d + 1];
        d2 += z[d + 2] * cp[d + 2];
        d3 += z[d + 3] * cp[d + 3];
      }
      float dist = z2 - 2.f * ((d0 + d1) + (d2 + d3)) + c2s[c0 + c];
      if (dist < best) { best = dist; bi = c0 + c; }
    }
  }
  cidx[beat] = bi;
  code_f[beat] = (float)bi;

  red[t] = best;
  __syncthreads();
  for (int s = 128; s > 0; s >>= 1) {
    if (t < s) red[t] += red[t + s];
    __syncthreads();
  }
  if (t == 0) atomicAdd(vq_accum, red[0] * inv_cnt);
}

__global__ void rhythm_k(const int* __restrict__ cidx, const int* __restrict__ rr,
                         const int* __restrict__ rrp, const float* __restrict__ hs,
                         const float* __restrict__ hc, const float* __restrict__ cemb,
                         const float* __restrict__ rremb, const float* __restrict__ rrpemb,
                         const float* __restrict__ hw, ushort_t* __restrict__ outh)
{
  int i = blockIdx.x * blockDim.x + threadIdx.x;
  if (i >= BM_ * RHY_D) return;
  int m = i >> 7, d = i & 127;
  float v = cemb[cidx[m] * RHY_D + d] + rremb[rr[m] * RHY_D + d] +
            rrpemb[rrp[m] * RHY_D + d] + hs[m] * hw[d] + hc[m] * hw[RHY_D + d];
  outh[i] = f2bf(gelu_t(v));
}

__global__ __launch_bounds__(512) void ep_mean_k(
    const ushort_t* __restrict__ ctxh, const ushort_t* __restrict__ rhyh,
    const int* __restrict__ neps, float* __restrict__ ctx_mean,
    float* __restrict__ rhy_mean)
{
  int be = blockIdx.x;
  int t = threadIdx.x;
  bool valid = (be & (E_ - 1)) < neps[be >> 7];
  if (t < EP_D) {
    float s = 0.f;
    for (int l = 0; l < EPL; ++l) s += bf2f(ctxh[((long)be * EPL + l) * EP_D + t]);
    ctx_mean[be * EP_D + t] = s * (1.0f / EPL);
  } else if (t < EP_D + RHY_D) {
    int d = t - EP_D;
    float s = 0.f;
    for (int l = 0; l < EPL; ++l) s += bf2f(rhyh[((long)be * EPL + l) * RHY_D + d]);
    rhy_mean[be * RHY_D + d] = valid ? s * (1.0f / EPL) : 0.f;
  }
}

__global__ __launch_bounds__(512) void day_k(const float* __restrict__ ec,
                                             const int* __restrict__ neps,
                                             float* __restrict__ day)
{
  int b = blockIdx.x, h = threadIdx.x;
  int n = neps[b];
  float s = 0.f;
  for (int e = 0; e < n; ++e) s += ec[((long)b * E_ + e) * DAY_D + h];
  day[b * DAY_D + h] = s / (float)(n > 0 ? n : 1);
}

extern "C" void kernel_launch(void* const* d_in, const int* in_sizes, int n_in,
                              void* d_out, int out_size, void* d_ws, size_t ws_size,
                              hipStream_t stream)
{
  (void)in_sizes; (void)n_in; (void)out_size; (void)ws_size;
  const float* windows  = (const float*)d_in[0];
  const float* metadata = (const float*)d_in[1];
  const int*   n_eps    = (const int*)d_in[3];
  const int*   rr_bins  = (const int*)d_in[4];
  const int*   rrp_bins = (const int*)d_in[5];
  const float* hour_sin = (const float*)d_in[6];
  const float* hour_cos = (const float*)d_in[7];
  const float* w_tok1 = (const float*)d_in[8];
  const float* b_tok1 = (const float*)d_in[9];
  const float* w_tok2 = (const float*)d_in[10];
  const float* b_tok2 = (const float*)d_in[11];
  const float* w_code = (const float*)d_in[12];
  const float* codebook = (const float*)d_in[13];
  const float* w_ep1 = (const float*)d_in[14];
  const float* b_ep1 = (const float*)d_in[15];
  const float* w_ep2 = (const float*)d_in[16];
  const float* b_ep2 = (const float*)d_in[17];
  const float* w_eptok = (const float*)d_in[18];
  const float* b_eptok = (const float*)d_in[19];
  const float* code_emb = (const float*)d_in[20];
  const float* rr_emb = (const float*)d_in[21];
  const float* rrp_emb = (const float*)d_in[22];
  const float* hour_w = (const float*)d_in[23];
  const float* w_fuse = (const float*)d_in[24];
  const float* b_fuse = (const float*)d_in[25];
  const float* w_day = (const float*)d_in[26];
  const float* b_day = (const float*)d_in[27];
  const float* w_bp1 = (const float*)d_in[28];
  const float* b_bp1 = (const float*)d_in[29];
  const float* w_bp2 = (const float*)d_in[30];
  const float* b_bp2 = (const float*)d_in[31];

  float* out = (float*)d_out;
  float* ws  = (float*)d_ws;

  // ---- workspace layout (float offsets; total 64,421,888 floats, same as R1) ----
  // lifetimes:  H [0..33.5M) dead after G2;  HEh/CTXh overlay H's first 25.2M;
  //             Z [25.2M..29.4M) dead after vq_k;  WT overlays Z (written AFTER vq_k);
  //             BE [33.5M..50.3M) dead after G3;  BPHh overlays BE (written in G6).
  float*    H     = ws;                                   // G1 out fp32 (65536x512)
  ushort_t* HEh   = (ushort_t*)ws;                        // G4 out bf16 (65536x384)
  ushort_t* CTXh  = (ushort_t*)(ws + 12582912L);          // G5 out bf16 (65536x384)
  float*    Z     = ws + 25165824L;                       // 65536x64 fp32 (dead after vq_k)
  ushort_t* WT    = (ushort_t*)(ws + 25165824L);          // bf16 weights; written after vq_k
  float*    BE    = ws + 33554432L;                       // 65536x256 fp32
  ushort_t* BPHh  = (ushort_t*)(ws + 33554432L);          // G6 out bf16, reuses BE
  ushort_t* BEh   = (ushort_t*)(ws + 50331648L);          // 65536x256 bf16
  ushort_t* RHYh  = (ushort_t*)(ws + 58720256L);          // 65536x128 bf16
  int*      CIDX  = (int*)(ws + 62914560L);
  float*    CMEAN = ws + 62980096L;
  float*    RMEAN = ws + 63373312L;
  float*    EPW   = ws + 63504384L;
  float*    FUSED = ws + 63897600L;

  ushort_t* wep1T = WT;                 // 384x256
  ushort_t* wep2T = WT + 98304L;        // 384x384
  ushort_t* wbp1T = WT + 245760L;       // 512x768
  ushort_t* wbp2T = WT + 638976L;       // 512x512 (ends at ushort 901,120 = 450,560 floats < Z's 4.19M)

  hipMemsetAsync((void*)(out + OFF_VQ), 0, sizeof(float), stream);

  dim3 blk(256);
  // G1: H = gelu(X @ w_tok1 + b)   65536 x 246 x 512  (fp32)
  gemm_f32_big<1, true, true, false><<<dim3(TOK_H / 128, BM_ / 128), blk, 0, stream>>>(
      windows, metadata, w_tok1, b_tok1, H, nullptr, BM_, TOK_H, WINF);
  // G2: BE = H @ w_tok2 + b        65536 x 512 x 256  (fp32, dual write bf16)
  gemm_f32_big<0, false, true, true><<<dim3(BEAT_D / 128, BM_ / 128), blk, 0, stream>>>(
      H, nullptr, w_tok2, b_tok2, BE, BEh, BM_, BEAT_D, TOK_H);
  // G3: Z = BE @ w_code            65536 x 256 x 64   (fp32)
  gemm_k<0, false, false, false><<<dim3(1, BM_ / 128), blk, 0, stream>>>(
      BE, nullptr, nullptr, w_code, nullptr, Z, BM_, CODE_D, BEAT_D);
  // VQ (consumes Z; Z dead after this)
  vq_k<<<dim3(BM_ / 256), blk, 0, stream>>>(Z, codebook, CIDX, out + OFF_CODE,
                                            out + OFF_VQ, 1.0f / (float)(BM_ * CODE_D));
  // weight prep AFTER vq_k, into Z's (now dead) region — fixes R2's WT/H aliasing NaN
  wtrans_k<<<dim3((BEAT_D * EP_D + 255) / 256), blk, 0, stream>>>(w_ep1, wep1T, BEAT_D, EP_D);
  wtrans_k<<<dim3((EP_D * EP_D + 255) / 256), blk, 0, stream>>>(w_ep2, wep2T, EP_D, EP_D);
  wtrans_k<<<dim3((768 * DAY_D + 255) / 256), blk, 0, stream>>>(w_bp1, wbp1T, 768, DAY_D);
  wtrans_k<<<dim3((DAY_D * DAY_D + 255) / 256), blk, 0, stream>>>(w_bp2, wbp2T, DAY_D, DAY_D);
  // rhythm -> bf16
  rhythm_k<<<dim3((BM_ * RHY_D) / 256), blk, 0, stream>>>(
      CIDX, rr_bins, rrp_bins, hour_sin, hour_cos, code_emb, rr_emb, rrp_emb, hour_w, RHYh);
  // G4: HEh = gelu(BEh @ w_ep1 + b)   bf16 MFMA, 65536 x 256 x 384
  gemm_bf16<0, true, false, 0><<<dim3(EP_D / 128, BM_ / 128), blk, 0, stream>>>(
      BEh, nullptr, nullptr, nullptr, wep1T, b_ep1, nullptr, HEh, EP_D, BEAT_D);
  // G5: CTXh = mask(HEh @ w_ep2 + b)  bf16 MFMA, 65536 x 384 x 384  (ctx_valid mask fused)
  gemm_bf16<0, false, true, 0><<<dim3(EP_D / 128, BM_ / 128), blk, 0, stream>>>(
      HEh, nullptr, nullptr, n_eps, wep2T, b_ep2, nullptr, CTXh, EP_D, EP_D);
  // episode means from bf16
  ep_mean_k<<<dim3(B_ * E_), dim3(512), 0, stream>>>(CTXh, RHYh, n_eps, CMEAN, RMEAN);
  // E2: ep_wave = mask(CMEAN @ w_eptok + b)  fp32 small
  gemm_k<0, false, true, true><<<dim3(EP_D / 64, (B_ * E_) / 128), blk, 0, stream>>>(
      CMEAN, nullptr, n_eps, w_eptok, b_eptok, EPW, B_ * E_, EP_D, EP_D);
  // E3: FUSED = gelu([EPW|RMEAN] @ w_fuse + b)
  gemm_k<3, true, true, false><<<dim3(DAY_D / 64, (B_ * E_) / 128), blk, 0, stream>>>(
      EPW, RMEAN, nullptr, w_fuse, b_fuse, FUSED, B_ * E_, DAY_D, EP_D + RHY_D);
  // E4: episode_ctx = FUSED @ w_day + b -> out
  gemm_k<0, false, true, false><<<dim3(DAY_D / 64, (B_ * E_) / 128), blk, 0, stream>>>(
      FUSED, nullptr, nullptr, w_day, b_day, out + OFF_EPCTX, B_ * E_, DAY_D, DAY_D);
  // E5: day_embed
  day_k<<<dim3(B_), dim3(DAY_D), 0, stream>>>(out + OFF_EPCTX, n_eps, out + OFF_DAY);
  // G6: BPHh = gelu([BEh|CTXh|RHYh] @ w_bp1 + b)  bf16 MFMA, 65536 x 768 x 512
  gemm_bf16<1, true, false, 0><<<dim3(DAY_D / 128, BM_ / 128), blk, 0, stream>>>(
      BEh, CTXh, RHYh, nullptr, wbp1T, b_bp1, nullptr, BPHh, DAY_D, 768);
  // G7: beat_repr = BPHh @ w_bp2 + b -> out fp32, 65536 x 512 x 512
  gemm_bf16<0, false, false, 1><<<dim3(DAY_D / 128, BM_ / 128), blk, 0, stream>>>(
      BPHh, nullptr, nullptr, nullptr, wbp2T, b_bp2, out, nullptr, DAY_D, DAY_D);
}